// Round 5
// baseline (306.124 us; speedup 1.0000x reference)
//
#include <hip/hip_runtime.h>

// ---- problem constants (match reference) ----
#define BEV_W    512
#define BEV_H    512
#define SCALE_XY (BEV_W * BEV_H)      // 262144
#define NPTS     400000
#define NFEAT    64
#define BATCH    2
#define NSEG     (BATCH * SCALE_XY)   // 524288

// ws layout: [0 .. NSEG*4) floats  : interleaved {sx,sy,sz,cnt} per voxel
//            [NSEG*4 .. )  floats  : bev image, NSEG*64 floats
#define SUMS_FLOATS ((size_t)NSEG * 4)
#define BEV_FLOATS  ((size_t)NSEG * 64)

// XLA lowers x / 0.2f to x * (1/0.2f), and 1/0.2f rounds to EXACTLY 5.0f.
// Mimic that so voxel indices / bilinear coords match the reference bit-for-bit.
__device__ __forceinline__ float coordf(float v) {
    return (v + 51.2f) * 5.0f;
}
__device__ __forceinline__ int vox_coord(float v) {
    return (int)floorf(coordf(v));
}

// ---------------- kernel A: per-voxel xyz sums + count ----------------
__global__ void __launch_bounds__(256)
kA_scatter_sums(const float* __restrict__ pts, float* __restrict__ sumsc) {
    int p = blockIdx.x * blockDim.x + threadIdx.x;
    if (p >= NPTS) return;
    const float* pp = pts + (size_t)p * 6;
    float b = pp[0], x = pp[1], y = pp[2], z = pp[3];
    int cx = vox_coord(x);
    int cy = vox_coord(y);
    int flat = (int)b * SCALE_XY + cy * BEV_W + cx;
    float* s4 = sumsc + (size_t)flat * 4;
    atomicAdd(s4 + 0, x);
    atomicAdd(s4 + 1, y);
    atomicAdd(s4 + 2, z);
    atomicAdd(s4 + 3, 1.0f);
}

// ---------------- kernel B: features -> matmul -> BN -> ReLU -> segment max ----------------
// 1 wave per point, lane = feature j (64 features).
__global__ void __launch_bounds__(256)
kB_pillar_max(const float* __restrict__ pts, const float* __restrict__ Wm,
              const float* __restrict__ gamma, const float* __restrict__ beta,
              const float* __restrict__ bmean, const float* __restrict__ bvar,
              const float* __restrict__ sumsc, unsigned int* __restrict__ bev) {
    __shared__ float sW[10 * 64];
    __shared__ float sScale[64];
    __shared__ float sShift[64];
    int tid = threadIdx.x;
    for (int i = tid; i < 640; i += 256) sW[i] = Wm[i];
    if (tid < 64) {
        float sc = gamma[tid] * rsqrtf(bvar[tid] + 0.001f);
        sScale[tid] = sc;
        sShift[tid] = beta[tid] - bmean[tid] * sc;
    }
    __syncthreads();

    int wid  = tid >> 6;
    int lane = tid & 63;
    int p = blockIdx.x * 4 + wid;
    if (p >= NPTS) return;

    const float* pp = pts + (size_t)p * 6;
    float x = pp[1], y = pp[2], z = pp[3], it = pp[4], tt = pp[5];
    int b = (int)pp[0];
    int cx = vox_coord(x);
    int cy = vox_coord(y);
    int flat = b * SCALE_XY + cy * BEV_W + cx;

    const float* s4 = sumsc + (size_t)flat * 4;
    float c = fmaxf(s4[3], 1.0f);
    float mx = s4[0] / c, my = s4[1] / c, mz = s4[2] / c;

    const float XOFF = 0.1f + -51.2f;   // voxel/2 + pc_min, f32 fold
    float fcx = x - ((float)cx * 0.2f + XOFF);
    float fcy = y - ((float)cy * 0.2f + XOFF);

    int j = lane;
    float h = x  * sW[0 * 64 + j]
            + y  * sW[1 * 64 + j]
            + z  * sW[2 * 64 + j]
            + it * sW[3 * 64 + j]
            + tt * sW[4 * 64 + j]
            + (x - mx) * sW[5 * 64 + j]
            + (y - my) * sW[6 * 64 + j]
            + (z - mz) * sW[7 * 64 + j]
            + fcx * sW[8 * 64 + j]
            + fcy * sW[9 * 64 + j];

    h = h * sScale[j] + sShift[j];
    h = fmaxf(h, 0.0f);

    // post-ReLU h >= 0: int bit ordering == float ordering; init 0 (= +0.0f)
    atomicMax((int*)(bev + (size_t)flat * 64 + j), __float_as_int(h));
}

// ---------------- kernel C: bilinear gather, f32 output ----------------
__global__ void __launch_bounds__(256)
kC_bilinear(const float* __restrict__ pts, const float* __restrict__ bev,
            float* __restrict__ out) {
    int tid  = threadIdx.x;
    int wid  = tid >> 6;
    int lane = tid & 63;
    int p = blockIdx.x * 4 + wid;
    if (p >= NPTS) return;

    const float* pp = pts + (size_t)p * 6;
    float x = pp[1], y = pp[2];
    int b = (int)pp[0];

    float px = coordf(x);
    float py = coordf(y);
    int fx = (int)floorf(px);
    int fy = (int)floorf(py);
    int x0 = min(max(fx, 0), BEV_W - 1);
    int x1 = min(max(fx + 1, 0), BEV_W - 1);
    int y0 = min(max(fy, 0), BEV_H - 1);
    int y1 = min(max(fy + 1, 0), BEV_H - 1);

    float wa = ((float)x1 - px) * ((float)y1 - py);
    float wb = ((float)x1 - px) * (py - (float)y0);
    float wc = (px - (float)x0) * ((float)y1 - py);
    float wd = (px - (float)x0) * (py - (float)y0);

    size_t base = (size_t)b * SCALE_XY * 64 + lane;
    float Ia = bev[base + (size_t)(y0 * BEV_W + x0) * 64];
    float Ib = bev[base + (size_t)(y1 * BEV_W + x0) * 64];
    float Ic = bev[base + (size_t)(y0 * BEV_W + x1) * 64];
    float Id = bev[base + (size_t)(y1 * BEV_W + x1) * 64];

    out[(size_t)p * 64 + lane] = Ia * wa + Ib * wb + Ic * wc + Id * wd;
}

extern "C" void kernel_launch(void* const* d_in, const int* in_sizes, int n_in,
                              void* d_out, int out_size, void* d_ws, size_t ws_size,
                              hipStream_t stream) {
    const float* pts   = (const float*)d_in[0];
    const float* Wm    = (const float*)d_in[1];
    const float* gamma = (const float*)d_in[2];
    const float* beta  = (const float*)d_in[3];
    const float* bmean = (const float*)d_in[4];
    const float* bvar  = (const float*)d_in[5];
    float* out = (float*)d_out;

    float* sumsc = (float*)d_ws;
    unsigned int* bev = (unsigned int*)((char*)d_ws + SUMS_FLOATS * sizeof(float));

    // zero sums+cnt (atomicAdd not idempotent across replays) and bev
    // (zero-init makes empty voxels 0 and atomicMax idempotent).
    hipMemsetAsync(d_ws, 0, (SUMS_FLOATS + BEV_FLOATS) * sizeof(float), stream);

    kA_scatter_sums<<<(NPTS + 255) / 256, 256, 0, stream>>>(pts, sumsc);
    kB_pillar_max<<<(NPTS + 3) / 4, 256, 0, stream>>>(pts, Wm, gamma, beta, bmean,
                                                      bvar, sumsc, bev);
    kC_bilinear<<<(NPTS + 3) / 4, 256, 0, stream>>>(pts, (const float*)bev, out);
}

// Round 6
// 306.064 us; speedup vs baseline: 1.0002x; 1.0002x over previous
//
#include <hip/hip_runtime.h>

// ---- problem constants (match reference) ----
#define BEV_W    512
#define BEV_H    512
#define SCALE_XY (BEV_W * BEV_H)      // 262144
#define NPTS     400000
#define NFEAT    64
#define BATCH    2
#define NSEG     (BATCH * SCALE_XY)   // 524288

// ws layout: [0 .. NSEG*4) floats  : interleaved {sx,sy,sz,cnt} per voxel
//            [NSEG*4 .. )  floats  : bev image, NSEG*64 floats
#define SUMS_FLOATS ((size_t)NSEG * 4)
#define BEV_FLOATS  ((size_t)NSEG * 64)

// XLA lowers x / 0.2f to x * (1/0.2f), and 1/0.2f rounds to EXACTLY 5.0f.
// Mimic that so voxel indices / bilinear coords match the reference bit-for-bit.
__device__ __forceinline__ float coordf(float v) {
    return (v + 51.2f) * 5.0f;
}
__device__ __forceinline__ int vox_coord(float v) {
    return (int)floorf(coordf(v));
}

// ---------------- kernel A: per-voxel xyz sums + count ----------------
__global__ void __launch_bounds__(256)
kA_scatter_sums(const float* __restrict__ pts, float* __restrict__ sumsc) {
    int p = blockIdx.x * blockDim.x + threadIdx.x;
    if (p >= NPTS) return;
    const float* pp = pts + (size_t)p * 6;
    float b = pp[0], x = pp[1], y = pp[2], z = pp[3];
    int cx = vox_coord(x);
    int cy = vox_coord(y);
    int flat = (int)b * SCALE_XY + cy * BEV_W + cx;
    float* s4 = sumsc + (size_t)flat * 4;
    atomicAdd(s4 + 0, x);
    atomicAdd(s4 + 1, y);
    atomicAdd(s4 + 2, z);
    atomicAdd(s4 + 3, 1.0f);
}

// ---------------- kernel B: features -> matmul -> BN -> ReLU -> segment max ----------------
// 1 wave per point, lane = feature j (64 features).
__global__ void __launch_bounds__(256)
kB_pillar_max(const float* __restrict__ pts, const float* __restrict__ Wm,
              const float* __restrict__ gamma, const float* __restrict__ beta,
              const float* __restrict__ bmean, const float* __restrict__ bvar,
              const float* __restrict__ sumsc, unsigned int* __restrict__ bev) {
    __shared__ float sW[10 * 64];
    __shared__ float sScale[64];
    __shared__ float sShift[64];
    int tid = threadIdx.x;
    for (int i = tid; i < 640; i += 256) sW[i] = Wm[i];
    if (tid < 64) {
        float sc = gamma[tid] * rsqrtf(bvar[tid] + 0.001f);
        sScale[tid] = sc;
        sShift[tid] = beta[tid] - bmean[tid] * sc;
    }
    __syncthreads();

    int wid  = tid >> 6;
    int lane = tid & 63;
    int p = blockIdx.x * 4 + wid;
    if (p >= NPTS) return;

    const float* pp = pts + (size_t)p * 6;
    float x = pp[1], y = pp[2], z = pp[3], it = pp[4], tt = pp[5];
    int b = (int)pp[0];
    int cx = vox_coord(x);
    int cy = vox_coord(y);
    int flat = b * SCALE_XY + cy * BEV_W + cx;

    const float* s4 = sumsc + (size_t)flat * 4;
    float c = fmaxf(s4[3], 1.0f);
    float mx = s4[0] / c, my = s4[1] / c, mz = s4[2] / c;

    const float XOFF = 0.1f + -51.2f;   // voxel/2 + pc_min, f32 fold
    float fcx = x - ((float)cx * 0.2f + XOFF);
    float fcy = y - ((float)cy * 0.2f + XOFF);

    int j = lane;
    float h = x  * sW[0 * 64 + j]
            + y  * sW[1 * 64 + j]
            + z  * sW[2 * 64 + j]
            + it * sW[3 * 64 + j]
            + tt * sW[4 * 64 + j]
            + (x - mx) * sW[5 * 64 + j]
            + (y - my) * sW[6 * 64 + j]
            + (z - mz) * sW[7 * 64 + j]
            + fcx * sW[8 * 64 + j]
            + fcy * sW[9 * 64 + j];

    h = h * sScale[j] + sShift[j];
    h = fmaxf(h, 0.0f);

    // post-ReLU h >= 0: int bit ordering == float ordering; init 0 (= +0.0f)
    atomicMax((int*)(bev + (size_t)flat * 64 + j), __float_as_int(h));
}

// ---------------- kernel C: bilinear gather, f32 output ----------------
__global__ void __launch_bounds__(256)
kC_bilinear(const float* __restrict__ pts, const float* __restrict__ bev,
            float* __restrict__ out) {
    int tid  = threadIdx.x;
    int wid  = tid >> 6;
    int lane = tid & 63;
    int p = blockIdx.x * 4 + wid;
    if (p >= NPTS) return;

    const float* pp = pts + (size_t)p * 6;
    float x = pp[1], y = pp[2];
    int b = (int)pp[0];

    float px = coordf(x);
    float py = coordf(y);
    int fx = (int)floorf(px);
    int fy = (int)floorf(py);
    int x0 = min(max(fx, 0), BEV_W - 1);
    int x1 = min(max(fx + 1, 0), BEV_W - 1);
    int y0 = min(max(fy, 0), BEV_H - 1);
    int y1 = min(max(fy + 1, 0), BEV_H - 1);

    float wa = ((float)x1 - px) * ((float)y1 - py);
    float wb = ((float)x1 - px) * (py - (float)y0);
    float wc = (px - (float)x0) * ((float)y1 - py);
    float wd = (px - (float)x0) * (py - (float)y0);

    size_t base = (size_t)b * SCALE_XY * 64 + lane;
    float Ia = bev[base + (size_t)(y0 * BEV_W + x0) * 64];
    float Ib = bev[base + (size_t)(y1 * BEV_W + x0) * 64];
    float Ic = bev[base + (size_t)(y0 * BEV_W + x1) * 64];
    float Id = bev[base + (size_t)(y1 * BEV_W + x1) * 64];

    out[(size_t)p * 64 + lane] = Ia * wa + Ib * wb + Ic * wc + Id * wd;
}

extern "C" void kernel_launch(void* const* d_in, const int* in_sizes, int n_in,
                              void* d_out, int out_size, void* d_ws, size_t ws_size,
                              hipStream_t stream) {
    const float* pts   = (const float*)d_in[0];
    const float* Wm    = (const float*)d_in[1];
    const float* gamma = (const float*)d_in[2];
    const float* beta  = (const float*)d_in[3];
    const float* bmean = (const float*)d_in[4];
    const float* bvar  = (const float*)d_in[5];
    float* out = (float*)d_out;

    float* sumsc = (float*)d_ws;
    unsigned int* bev = (unsigned int*)((char*)d_ws + SUMS_FLOATS * sizeof(float));

    // zero sums+cnt (atomicAdd not idempotent across replays) and bev
    // (zero-init makes empty voxels 0 and atomicMax idempotent).
    hipMemsetAsync(d_ws, 0, (SUMS_FLOATS + BEV_FLOATS) * sizeof(float), stream);

    kA_scatter_sums<<<(NPTS + 255) / 256, 256, 0, stream>>>(pts, sumsc);
    kB_pillar_max<<<(NPTS + 3) / 4, 256, 0, stream>>>(pts, Wm, gamma, beta, bmean,
                                                      bvar, sumsc, bev);
    kC_bilinear<<<(NPTS + 3) / 4, 256, 0, stream>>>(pts, (const float*)bev, out);
}